// Round 20
// baseline (154.631 us; speedup 1.0000x reference)
//
#include <hip/hip_runtime.h>
#include <math.h>

#define N_TOK 2048
#define DM    1024
#define HD    2048
#define NE    8
#define RMAX  5120                /* 4096 + 8*128 pad */
#define TMAX  40                  /* max 128-row tiles */
#define KSPL  2                   /* ffn2 K-split */

#define GATE_BLKS 512             /* N_TOK/4 */
#define XCVT_BLKS 1024            /* N_TOK*DM/(256*8) */
#define PREP_BLKS (GATE_BLKS + XCVT_BLKS)
#define WCV2_BLKS 512             /* W2: 8e x 64 k-tiles, 1024 thr */
#define WCV1_BLKS 512             /* W1: 8e x 32 k-tiles x 2 col-tiles */

typedef short short8 __attribute__((ext_vector_type(8)));
typedef unsigned short u16x8 __attribute__((ext_vector_type(8)));
typedef float f32x4  __attribute__((ext_vector_type(4)));

__device__ inline unsigned short f2b(float f) {   // fp32 -> bf16 RNE
  unsigned int u = __float_as_uint(f);
  return (unsigned short)((u + 0x7FFFu + ((u >> 16) & 1u)) >> 16);
}
__device__ inline float b2f(unsigned short s) {
  return __uint_as_float(((unsigned int)s) << 16);
}
__device__ inline void gload_lds16(const void* g, void* l) {
  __builtin_amdgcn_global_load_lds(
      (const __attribute__((address_space(1))) unsigned int*)g,
      (__attribute__((address_space(3))) unsigned int*)l, 16, 0, 0);
}

// ---------------------------------------------------------------- prep
// gate (512 blocks) + x-convert (1024 blocks). R18 exact.
__global__ __launch_bounds__(256) void prep_kernel(
    const float* __restrict__ inp, const float* __restrict__ Wg,
    const float* __restrict__ bg,
    int* __restrict__ top_idx, float* __restrict__ gate_w,
    unsigned short* __restrict__ Xb) {
  int bid = blockIdx.x;
  if (bid < GATE_BLKS) {
    int wave = threadIdx.x >> 6;
    int lane = threadIdx.x & 63;
    int n = bid * 4 + wave;
    float acc[NE];
#pragma unroll
    for (int e = 0; e < NE; ++e) acc[e] = 0.f;
    const float4* wg4 = reinterpret_cast<const float4*>(Wg);
#pragma unroll
    for (int i = 0; i < DM / 64; ++i) {
      int d = i * 64 + lane;
      float x = inp[n * DM + d];
      float4 w0 = wg4[d * 2 + 0];
      float4 w1 = wg4[d * 2 + 1];
      acc[0] += x * w0.x; acc[1] += x * w0.y; acc[2] += x * w0.z; acc[3] += x * w0.w;
      acc[4] += x * w1.x; acc[5] += x * w1.y; acc[6] += x * w1.z; acc[7] += x * w1.w;
    }
#pragma unroll
    for (int off = 32; off > 0; off >>= 1) {
#pragma unroll
      for (int e = 0; e < NE; ++e) acc[e] += __shfl_xor(acc[e], off);
    }
    if (lane == 0) {
      float v0 = -1e30f, v1 = -1e30f; int i0 = -1, i1 = -1;
#pragma unroll
      for (int e = 0; e < NE; ++e) {
        float v = acc[e] + bg[e];
        if (v > v0)      { v1 = v0; i1 = i0; v0 = v; i0 = e; }
        else if (v > v1) { v1 = v;  i1 = e; }
      }
      float e1 = expf(v1 - v0);
      float s  = 1.f + e1;
      top_idx[n * 2]     = i0;
      top_idx[n * 2 + 1] = i1;
      gate_w[n * 2]      = 1.f / s;
      gate_w[n * 2 + 1]  = e1 / s;
    }
  } else {
    int i = ((bid - GATE_BLKS) * 256 + threadIdx.x) * 8;
    float4 a = *(const float4*)(inp + i);
    float4 b = *(const float4*)(inp + i + 4);
    ushort4 pa, pb;
    pa.x = f2b(a.x); pa.y = f2b(a.y); pa.z = f2b(a.z); pa.w = f2b(a.w);
    pb.x = f2b(b.x); pb.y = f2b(b.y); pb.z = f2b(b.z); pb.w = f2b(b.w);
    *(ushort4*)(Xb + i)     = pa;
    *(ushort4*)(Xb + i + 4) = pb;
  }
}

// ---------------------------------------------------------------- wcvt1
// Standalone: W1 [DM][HD] fp32 -> k-chunked bf16, 512 blocks x 1024 thr.
// chunk (kb,n) = 8 consecutive k for col n at ((kb*HD)+n)*8.
__global__ __launch_bounds__(1024) void wcvt1_kernel(
    const float* __restrict__ W1, unsigned short* __restrict__ W1C) {
  int wb = blockIdx.x;                     // 0..511
  int z  = wb >> 6;                        // expert
  int r  = wb & 63;                        // 32 k-tiles x 2 col-tiles
  const float* src = W1 + (size_t)z * DM * HD;
  unsigned short* dst = W1C + (size_t)z * DM * HD;
  int n0 = (r & 1) * 1024, k0 = (r >> 1) * 32;
  int t  = threadIdx.x;
  int cg = t & 255, kg = t >> 8;           // 256 col-groups x 4 k-groups
  const float* s = src + (size_t)(k0 + kg * 8) * HD + n0 + cg * 4;
  float4 v[8];
#pragma unroll
  for (int i = 0; i < 8; ++i) v[i] = *(const float4*)(s + (size_t)i * HD);
#pragma unroll
  for (int c = 0; c < 4; ++c) {
    u16x8 o;
    o[0] = f2b(v[0][c]); o[1] = f2b(v[1][c]); o[2] = f2b(v[2][c]); o[3] = f2b(v[3][c]);
    o[4] = f2b(v[4][c]); o[5] = f2b(v[5][c]); o[6] = f2b(v[6][c]); o[7] = f2b(v[7][c]);
    *(u16x8*)(dst + ((size_t)(k0 / 8 + kg) * HD + n0 + cg * 4 + c) * 8) = o;
  }
}

// ---------------------------------------------------------------- group (+wcvt2 riders)
// Block 0: single-block deterministic bucketing (1024-thread scan).
// Blocks 1..512: convert W2 -> k-chunked bf16. R18 exact.
__global__ __launch_bounds__(1024) void group_kernel(
    const int* __restrict__ top_idx,
    const float* __restrict__ W2,
    int* __restrict__ token_of, int* __restrict__ inv_g,
    int* __restrict__ tile_expert, int* __restrict__ tile_row0,
    int* __restrict__ n_tiles,
    unsigned short* __restrict__ W2C) {
  if (blockIdx.x != 0) {
    int wb = blockIdx.x - 1;                 // 0..511
    int z  = wb >> 6;                        // expert
    int k0 = (wb & 63) * 32;
    const float* src = W2 + (size_t)z * HD * DM;
    unsigned short* dst = W2C + (size_t)z * HD * DM;
    int t  = threadIdx.x;
    int cg = t & 255, kg = t >> 8;           // 256 col-groups x 4 k-groups
    const float* s = src + (size_t)(k0 + kg * 8) * DM + cg * 4;
    float4 v[8];
#pragma unroll
    for (int i = 0; i < 8; ++i) v[i] = *(const float4*)(s + (size_t)i * DM);
#pragma unroll
    for (int c = 0; c < 4; ++c) {
      u16x8 o;
      o[0] = f2b(v[0][c]); o[1] = f2b(v[1][c]); o[2] = f2b(v[2][c]); o[3] = f2b(v[3][c]);
      o[4] = f2b(v[4][c]); o[5] = f2b(v[5][c]); o[6] = f2b(v[6][c]); o[7] = f2b(v[7][c]);
      *(u16x8*)(dst + ((size_t)(k0 / 8 + kg) * DM + cg * 4 + c) * 8) = o;
    }
    return;
  }
  __shared__ int s_wtot[16];
  int tid = threadIdx.x, lane = tid & 63, wid = tid >> 6;
  int base = 0, tiles = 0;
  for (int e = 0; e < NE; ++e) {
    int cnt = 0;
#pragma unroll
    for (int c0 = 0; c0 < N_TOK; c0 += 1024) {
      int n = c0 + tid;
      int t0 = top_idx[n * 2], t1 = top_idx[n * 2 + 1];
      bool f = (t0 == e) || (t1 == e);
      int k = (t0 == e) ? 0 : 1;
      unsigned long long m = __ballot(f);
      int lp = __popcll(m & ((1ull << lane) - 1ull));
      if (lane == 0) s_wtot[wid] = __popcll(m);
      __syncthreads();
      int wbase = 0, tot = 0;
#pragma unroll
      for (int w = 0; w < 16; ++w) {
        int c = s_wtot[w];
        if (w < wid) wbase += c;
        tot += c;
      }
      if (f) {
        int pos = base + cnt + wbase + lp;
        token_of[pos] = n;
        inv_g[n * 2 + k] = pos;
      }
      cnt += tot;
      __syncthreads();
    }
    int padded = (cnt + 127) & ~127;
    for (int i = cnt + tid; i < padded; i += 1024) token_of[base + i] = -1;
    if (tid == 0) {
      for (int t = 0; t < padded / 128; ++t) {
        tile_expert[tiles + t] = e;
        tile_row0[tiles + t]   = base + t * 128;
      }
    }
    tiles += padded / 128;
    base  += padded;
    __syncthreads();
  }
  if (tid == 0) n_tiles[0] = tiles;
}

// ---------------------------------------------------------------- ffn1
// R19-verified: 128x64 tile, BK=32, dbuf, XCD swizzle, both operands bf16
// via pure global_load_lds (A: Xb slot-swizzled; B: W1C k-chunked).
__global__ __launch_bounds__(256, 6) void ffn1_mfma(
    const unsigned short* __restrict__ Xb,
    const unsigned short* __restrict__ W1C,
    const float* __restrict__ b1,
    const unsigned short* __restrict__ Xzero,
    const int* __restrict__ token_of, const int* __restrict__ tile_expert,
    const int* __restrict__ tile_row0, const int* __restrict__ n_tiles,
    unsigned short* __restrict__ Hbuf) {
  int lin  = blockIdx.x;
  int xcd  = lin & 7, slot = lin >> 3;
  int unit = xcd * 4 + slot / TMAX;        // 0..31 col unit
  int t    = slot % TMAX;
  if (t >= n_tiles[0]) return;
  int e    = tile_expert[t];
  int row0 = tile_row0[t];
  int h0   = unit * 64;
  __shared__ __align__(16) unsigned short Asl[2][128][32];
  __shared__ __align__(16) unsigned short Bsl[2][4][64][8];
  int tid = threadIdx.x, lane = tid & 63;
  int wid = tid >> 6, wr = wid >> 1, wc = wid & 1;
  int l15 = lane & 15, l4 = lane >> 4;
  int sw  = (l15 >> 1) & 3;

  int ar[2], asg[2], tk[2];
#pragma unroll
  for (int q = 0; q < 2; ++q) {
    int idx = tid + q * 256;
    ar[q]  = idx >> 2;
    asg[q] = (idx & 3) ^ ((ar[q] >> 1) & 3);
    tk[q]  = token_of[row0 + ar[q]];
  }
  int bcol = tid & 63, bks = tid >> 6;
  const unsigned short* W1e = W1C + (size_t)e * DM * HD;

  f32x4 acc[4][2] = {};

  auto issueAB = [&](int tt, int buf) {
#pragma unroll
    for (int q = 0; q < 2; ++q) {
      int idx = tid + q * 256;
      const unsigned short* ga = (tk[q] < 0)
          ? Xzero
          : Xb + (size_t)tk[q] * DM + tt * 32 + asg[q] * 8;
      gload_lds16(ga, (char*)&Asl[buf][0][0] + (size_t)idx * 16);
    }
    const unsigned short* gb =
        W1e + ((size_t)(tt * 4 + bks) * HD + h0 + bcol) * 8;
    gload_lds16(gb, (char*)&Bsl[buf][0][0] + (size_t)tid * 16);
  };
  auto compute = [&](int buf) {
    short8 a[4], b[2];
#pragma unroll
    for (int m = 0; m < 4; ++m) {
      int R = wr * 64 + m * 16 + l15;
      a[m] = *(const short8*)((const char*)&Asl[buf][0][0] + R * 64 + ((l4 ^ sw) << 4));
    }
#pragma unroll
    for (int n = 0; n < 2; ++n)
      b[n] = *(const short8*)&Bsl[buf][l4][wc * 32 + n * 16 + l15][0];
#pragma unroll
    for (int m = 0; m < 4; ++m)
#pragma unroll
      for (int n = 0; n < 2; ++n)
        acc[m][n] = __builtin_amdgcn_mfma_f32_16x16x32_bf16(a[m], b[n], acc[m][n], 0, 0, 0);
  };

  issueAB(0, 0);
  for (int kt = 0; kt < 32; kt += 2) {
    __syncthreads();
    if (kt + 1 < 32) issueAB(kt + 1, 1);
    compute(0);
    __syncthreads();
    if (kt + 2 < 32) issueAB(kt + 2, 0);
    compute(1);
  }

  float bias[2];
#pragma unroll
  for (int n = 0; n < 2; ++n) bias[n] = b1[e * HD + h0 + wc * 32 + n * 16 + l15];
#pragma unroll
  for (int m = 0; m < 4; ++m) {
#pragma unroll
    for (int n = 0; n < 2; ++n) {
      int col = h0 + wc * 32 + n * 16 + l15;
#pragma unroll
      for (int j = 0; j < 4; ++j) {
        int row = row0 + wr * 64 + m * 16 + l4 * 4 + j;
        float x = acc[m][n][j] + bias[n];
        float g = 0.5f * x * (1.f + tanhf(0.7978845608f * (x + 0.044715f * x * x * x)));
        Hbuf[(size_t)row * HD + col] = f2b(g);
      }
    }
  }
}

// ---------------------------------------------------------------- ffn2
// R18 exact: both operands bf16 via pure global_load_lds; K-split x2;
// fp32 partials; bias ks==0 only.
__global__ __launch_bounds__(256, 6) void ffn2_mfma(
    const unsigned short* __restrict__ Hbuf,
    const unsigned short* __restrict__ W2C,
    const float* __restrict__ b2,
    const int* __restrict__ tile_expert, const int* __restrict__ tile_row0,
    const int* __restrict__ n_tiles,
    float* __restrict__ Ypart) {
  int lin  = blockIdx.x;
  int xcd  = lin & 7, slot = lin >> 3;
  int unit = xcd * 4 + slot / TMAX;        // 0..31
  int t    = slot % TMAX;
  if (t >= n_tiles[0]) return;
  int e    = tile_expert[t];
  int row0 = tile_row0[t];
  int d0   = (unit >> 1) * 64;
  int ks   = unit & 1;
  int kbase = ks * (HD / KSPL);            // 0 or 1024
  int kb0   = kbase >> 3;                  // chunk-row base
  __shared__ __align__(16) unsigned short Asl[2][128][32];
  __shared__ __align__(16) unsigned short Bsl[2][4][64][8];
  int tid = threadIdx.x, lane = tid & 63;
  int wid = tid >> 6, wr = wid >> 1, wc = wid & 1;
  int l15 = lane & 15, l4 = lane >> 4;
  int sw  = (l15 >> 1) & 3;

  int ar[2], asg[2];
#pragma unroll
  for (int q = 0; q < 2; ++q) {
    int idx = tid + q * 256;
    ar[q]  = idx >> 2;
    asg[q] = (idx & 3) ^ ((ar[q] >> 1) & 3);
  }
  int bcol = tid & 63, bks = tid >> 6;
  const unsigned short* W2e = W2C + (size_t)e * HD * DM;

  f32x4 acc[4][2] = {};

  auto issueAB = [&](int tt, int buf) {
#pragma unroll
    for (int q = 0; q < 2; ++q) {
      int idx = tid + q * 256;
      const unsigned short* ga =
          Hbuf + (size_t)(row0 + ar[q]) * HD + kbase + tt * 32 + asg[q] * 8;
      gload_lds16(ga, (char*)&Asl[buf][0][0] + (size_t)idx * 16);
    }
    const unsigned short* gb =
        W2e + ((size_t)(kb0 + tt * 4 + bks) * DM + d0 + bcol) * 8;
    gload_lds16(gb, (char*)&Bsl[buf][0][0] + (size_t)tid * 16);
  };
  auto compute = [&](int buf) {
    short8 a[4], b[2];
#pragma unroll
    for (int m = 0; m < 4; ++m) {
      int R = wr * 64 + m * 16 + l15;
      a[m] = *(const short8*)((const char*)&Asl[buf][0][0] + R * 64 + ((l4 ^ sw) << 4));
    }
#pragma unroll
    for (int n = 0; n < 2; ++n)
      b[n] = *(const short8*)&Bsl[buf][l4][wc * 32 + n * 16 + l15][0];
#pragma unroll
    for (int m = 0; m < 4; ++m)
#pragma unroll
      for (int n = 0; n < 2; ++n)
        acc[m][n] = __builtin_amdgcn_mfma_f32_16x16x32_bf16(a[m], b[n], acc[m][n], 0, 0, 0);
  };

  const int NT = HD / KSPL / 32;           // 32 K-steps
  issueAB(0, 0);
  for (int kt = 0; kt < NT; kt += 2) {
    __syncthreads();                       // drains vmcnt: buf0 ready
    if (kt + 1 < NT) issueAB(kt + 1, 1);
    compute(0);
    __syncthreads();                       // buf1 ready; buf0 free
    if (kt + 2 < NT) issueAB(kt + 2, 0);
    compute(1);
  }

  float bias[2];
#pragma unroll
  for (int n = 0; n < 2; ++n)
    bias[n] = (ks == 0) ? b2[e * DM + d0 + wc * 32 + n * 16 + l15] : 0.f;
  float* Yp = Ypart + (size_t)ks * RMAX * DM;
#pragma unroll
  for (int m = 0; m < 4; ++m) {
#pragma unroll
    for (int n = 0; n < 2; ++n) {
      int col = d0 + wc * 32 + n * 16 + l15;
#pragma unroll
      for (int j = 0; j < 4; ++j) {
        int row = row0 + wr * 64 + m * 16 + l4 * 4 + j;
        Yp[(size_t)row * DM + col] = acc[m][n][j] + bias[n];
      }
    }
  }
}

// ---------------------------------------------------------------- combine
__global__ void combine_kernel(const float* __restrict__ Ypart,
                               const int* __restrict__ inv_g,
                               const float* __restrict__ gate_w,
                               float* __restrict__ out) {
  int n = blockIdx.x;
  int r0 = inv_g[n * 2], r1 = inv_g[n * 2 + 1];
  float g0 = gate_w[n * 2], g1 = gate_w[n * 2 + 1];
  int i = threadIdx.x;
  const float4* y00 = (const float4*)(Ypart + (size_t)r0 * DM);
  const float4* y01 = (const float4*)(Ypart + (size_t)(RMAX + r0) * DM);
  const float4* y10 = (const float4*)(Ypart + (size_t)r1 * DM);
  const float4* y11 = (const float4*)(Ypart + (size_t)(RMAX + r1) * DM);
  float4 a0 = y00[i], a1 = y01[i], b0 = y10[i], b1 = y11[i];
  float4 rv;
  rv.x = g0 * (a0.x + a1.x) + g1 * (b0.x + b1.x);
  rv.y = g0 * (a0.y + a1.y) + g1 * (b0.y + b1.y);
  rv.z = g0 * (a0.z + a1.z) + g1 * (b0.z + b1.z);
  rv.w = g0 * (a0.w + a1.w) + g1 * (b0.w + b1.w);
  *(float4*)(out + (size_t)n * DM + i * 4) = rv;
}

// ---------------------------------------------------------------- launch
extern "C" void kernel_launch(void* const* d_in, const int* in_sizes, int n_in,
                              void* d_out, int out_size, void* d_ws, size_t ws_size,
                              hipStream_t stream) {
  const float* inp = (const float*)d_in[0];
  const float* Wg  = (const float*)d_in[1];
  const float* bg  = (const float*)d_in[2];
  const float* W1  = (const float*)d_in[3];
  const float* b1  = (const float*)d_in[4];
  const float* W2  = (const float*)d_in[5];
  const float* b2  = (const float*)d_in[6];
  float* out = (float*)d_out;

  char* ws = (char*)d_ws;
  size_t off = 0;
  auto alloc = [&](size_t bytes) {
    size_t o = off;
    off = (off + bytes + 255) & ~(size_t)255;
    return o;
  };
  int*   top_idx     = (int*)  (ws + alloc(N_TOK * 2 * sizeof(int)));
  float* gate_w      = (float*)(ws + alloc(N_TOK * 2 * sizeof(float)));
  int*   token_of    = (int*)  (ws + alloc(RMAX * sizeof(int)));
  int*   inv_g       = (int*)  (ws + alloc(N_TOK * 2 * sizeof(int)));
  int*   tile_expert = (int*)  (ws + alloc(TMAX * sizeof(int)));
  int*   tile_row0   = (int*)  (ws + alloc(TMAX * sizeof(int)));
  int*   n_tiles     = (int*)  (ws + alloc(sizeof(int)));
  unsigned short* Xzero = (unsigned short*)(ws + alloc(DM * 2));
  unsigned short* Xb    = (unsigned short*)(ws + alloc((size_t)N_TOK * DM * 2));
  unsigned short* W1C   = (unsigned short*)(ws + alloc((size_t)NE * DM * HD * 2));
  unsigned short* W2C   = (unsigned short*)(ws + alloc((size_t)NE * HD * DM * 2));
  unsigned short* Hbuf  = (unsigned short*)(ws + alloc((size_t)RMAX * HD * 2));
  float*          Ypart = (float*)(ws + alloc((size_t)KSPL * RMAX * DM * 4));
  (void)ws_size;

  hipMemsetAsync(Xzero, 0, DM * 2, stream);
  prep_kernel<<<PREP_BLKS, 256, 0, stream>>>(inp, Wg, bg, top_idx, gate_w, Xb);
  wcvt1_kernel<<<WCV1_BLKS, 1024, 0, stream>>>(W1, W1C);
  group_kernel<<<1 + WCV2_BLKS, 1024, 0, stream>>>(
      top_idx, W2, token_of, inv_g, tile_expert, tile_row0, n_tiles, W2C);
  ffn1_mfma<<<8 * 4 * TMAX, 256, 0, stream>>>(
      Xb, W1C, b1, Xzero, token_of, tile_expert, tile_row0, n_tiles, Hbuf);
  ffn2_mfma<<<8 * 4 * TMAX, 256, 0, stream>>>(
      Hbuf, W2C, b2, tile_expert, tile_row0, n_tiles, Ypart);
  combine_kernel<<<N_TOK, 256, 0, stream>>>(Ypart, inv_g, gate_w, out);
}

// Round 21
// 137.040 us; speedup vs baseline: 1.1284x; 1.1284x over previous
//
#include <hip/hip_runtime.h>
#include <math.h>

#define N_TOK 2048
#define DM    1024
#define HD    2048
#define NE    8
#define RMAX  5120                /* 4096 + 8*128 pad */
#define TMAX  40                  /* max 128-row tiles */
#define KSPL  2                   /* ffn2 K-split */

#define GATE_BLKS 512             /* N_TOK/4 */
#define XCVT_BLKS 1024            /* N_TOK*DM/(256*8) */
#define PREP_BLKS (GATE_BLKS + XCVT_BLKS)
#define WCV2_BLKS 512             /* W2: 8e x 64 k-tiles, 1024 thr */

typedef short short8 __attribute__((ext_vector_type(8)));
typedef unsigned short u16x8 __attribute__((ext_vector_type(8)));
typedef float f32x4  __attribute__((ext_vector_type(4)));

__device__ inline unsigned short f2b(float f) {   // fp32 -> bf16 RNE
  unsigned int u = __float_as_uint(f);
  return (unsigned short)((u + 0x7FFFu + ((u >> 16) & 1u)) >> 16);
}
__device__ inline float b2f(unsigned short s) {
  return __uint_as_float(((unsigned int)s) << 16);
}
__device__ inline void gload_lds16(const void* g, void* l) {
  __builtin_amdgcn_global_load_lds(
      (const __attribute__((address_space(1))) unsigned int*)g,
      (__attribute__((address_space(3))) unsigned int*)l, 16, 0, 0);
}

// ---------------------------------------------------------------- prep
// gate (512 blocks) + x-convert (1024 blocks). R18 exact.
__global__ __launch_bounds__(256) void prep_kernel(
    const float* __restrict__ inp, const float* __restrict__ Wg,
    const float* __restrict__ bg,
    int* __restrict__ top_idx, float* __restrict__ gate_w,
    unsigned short* __restrict__ Xb) {
  int bid = blockIdx.x;
  if (bid < GATE_BLKS) {
    int wave = threadIdx.x >> 6;
    int lane = threadIdx.x & 63;
    int n = bid * 4 + wave;
    float acc[NE];
#pragma unroll
    for (int e = 0; e < NE; ++e) acc[e] = 0.f;
    const float4* wg4 = reinterpret_cast<const float4*>(Wg);
#pragma unroll
    for (int i = 0; i < DM / 64; ++i) {
      int d = i * 64 + lane;
      float x = inp[n * DM + d];
      float4 w0 = wg4[d * 2 + 0];
      float4 w1 = wg4[d * 2 + 1];
      acc[0] += x * w0.x; acc[1] += x * w0.y; acc[2] += x * w0.z; acc[3] += x * w0.w;
      acc[4] += x * w1.x; acc[5] += x * w1.y; acc[6] += x * w1.z; acc[7] += x * w1.w;
    }
#pragma unroll
    for (int off = 32; off > 0; off >>= 1) {
#pragma unroll
      for (int e = 0; e < NE; ++e) acc[e] += __shfl_xor(acc[e], off);
    }
    if (lane == 0) {
      float v0 = -1e30f, v1 = -1e30f; int i0 = -1, i1 = -1;
#pragma unroll
      for (int e = 0; e < NE; ++e) {
        float v = acc[e] + bg[e];
        if (v > v0)      { v1 = v0; i1 = i0; v0 = v; i0 = e; }
        else if (v > v1) { v1 = v;  i1 = e; }
      }
      float e1 = expf(v1 - v0);
      float s  = 1.f + e1;
      top_idx[n * 2]     = i0;
      top_idx[n * 2 + 1] = i1;
      gate_w[n * 2]      = 1.f / s;
      gate_w[n * 2 + 1]  = e1 / s;
    }
  } else {
    int i = ((bid - GATE_BLKS) * 256 + threadIdx.x) * 8;
    float4 a = *(const float4*)(inp + i);
    float4 b = *(const float4*)(inp + i + 4);
    ushort4 pa, pb;
    pa.x = f2b(a.x); pa.y = f2b(a.y); pa.z = f2b(a.z); pa.w = f2b(a.w);
    pb.x = f2b(b.x); pb.y = f2b(b.y); pb.z = f2b(b.z); pb.w = f2b(b.w);
    *(ushort4*)(Xb + i)     = pa;
    *(ushort4*)(Xb + i + 4) = pb;
  }
}

// ---------------------------------------------------------------- group (+wcvt2 riders)
// Block 0: single-block bucketing scan. Blocks 1..512: W2 -> k-chunked
// bf16 on otherwise-idle CUs. R18 exact.
__global__ __launch_bounds__(1024) void group_kernel(
    const int* __restrict__ top_idx,
    const float* __restrict__ W2,
    int* __restrict__ token_of, int* __restrict__ inv_g,
    int* __restrict__ tile_expert, int* __restrict__ tile_row0,
    int* __restrict__ n_tiles,
    unsigned short* __restrict__ W2C) {
  if (blockIdx.x != 0) {
    int wb = blockIdx.x - 1;                 // 0..511
    int z  = wb >> 6;                        // expert
    int k0 = (wb & 63) * 32;
    const float* src = W2 + (size_t)z * HD * DM;
    unsigned short* dst = W2C + (size_t)z * HD * DM;
    int t  = threadIdx.x;
    int cg = t & 255, kg = t >> 8;           // 256 col-groups x 4 k-groups
    const float* s = src + (size_t)(k0 + kg * 8) * DM + cg * 4;
    float4 v[8];
#pragma unroll
    for (int i = 0; i < 8; ++i) v[i] = *(const float4*)(s + (size_t)i * DM);
#pragma unroll
    for (int c = 0; c < 4; ++c) {
      u16x8 o;
      o[0] = f2b(v[0][c]); o[1] = f2b(v[1][c]); o[2] = f2b(v[2][c]); o[3] = f2b(v[3][c]);
      o[4] = f2b(v[4][c]); o[5] = f2b(v[5][c]); o[6] = f2b(v[6][c]); o[7] = f2b(v[7][c]);
      *(u16x8*)(dst + ((size_t)(k0 / 8 + kg) * DM + cg * 4 + c) * 8) = o;
    }
    return;
  }
  __shared__ int s_wtot[16];
  int tid = threadIdx.x, lane = tid & 63, wid = tid >> 6;
  int base = 0, tiles = 0;
  for (int e = 0; e < NE; ++e) {
    int cnt = 0;
#pragma unroll
    for (int c0 = 0; c0 < N_TOK; c0 += 1024) {
      int n = c0 + tid;
      int t0 = top_idx[n * 2], t1 = top_idx[n * 2 + 1];
      bool f = (t0 == e) || (t1 == e);
      int k = (t0 == e) ? 0 : 1;
      unsigned long long m = __ballot(f);
      int lp = __popcll(m & ((1ull << lane) - 1ull));
      if (lane == 0) s_wtot[wid] = __popcll(m);
      __syncthreads();
      int wbase = 0, tot = 0;
#pragma unroll
      for (int w = 0; w < 16; ++w) {
        int c = s_wtot[w];
        if (w < wid) wbase += c;
        tot += c;
      }
      if (f) {
        int pos = base + cnt + wbase + lp;
        token_of[pos] = n;
        inv_g[n * 2 + k] = pos;
      }
      cnt += tot;
      __syncthreads();
    }
    int padded = (cnt + 127) & ~127;
    for (int i = cnt + tid; i < padded; i += 1024) token_of[base + i] = -1;
    if (tid == 0) {
      for (int t = 0; t < padded / 128; ++t) {
        tile_expert[tiles + t] = e;
        tile_row0[tiles + t]   = base + t * 128;
      }
    }
    tiles += padded / 128;
    base  += padded;
    __syncthreads();
  }
  if (tid == 0) n_tiles[0] = tiles;
}

// ---------------------------------------------------------------- ffn1
// R18 structure + 3-deep B-register prefetch (bv[3][8], full unroll):
// packwrite(t) uses regs completed at sync(t-1); in-flight loads drain
// with A at the single barrier. LDS/barrier/traffic identical to R18.
__global__ __launch_bounds__(256, 6) void ffn1_mfma(
    const unsigned short* __restrict__ Xb,
    const float* __restrict__ W1,
    const float* __restrict__ b1,
    const unsigned short* __restrict__ Xzero,
    const int* __restrict__ token_of, const int* __restrict__ tile_expert,
    const int* __restrict__ tile_row0, const int* __restrict__ n_tiles,
    unsigned short* __restrict__ Hbuf) {
  int lin  = blockIdx.x;
  int xcd  = lin & 7, slot = lin >> 3;
  int unit = xcd * 4 + slot / TMAX;        // 0..31 col unit
  int t    = slot % TMAX;
  if (t >= n_tiles[0]) return;
  int e    = tile_expert[t];
  int row0 = tile_row0[t];
  int h0   = unit * 64;
  __shared__ __align__(16) unsigned short Asl[2][128][32];
  __shared__ __align__(16) unsigned short Bsl[2][4][64][8];
  int tid = threadIdx.x, lane = tid & 63;
  int wid = tid >> 6, wr = wid >> 1, wc = wid & 1;
  int l15 = lane & 15, l4 = lane >> 4;
  int sw  = (l15 >> 1) & 3;

  int ar[2], asg[2], tk[2];
#pragma unroll
  for (int q = 0; q < 2; ++q) {
    int idx = tid + q * 256;
    ar[q]  = idx >> 2;
    asg[q] = (idx & 3) ^ ((ar[q] >> 1) & 3);
    tk[q]  = token_of[row0 + ar[q]];
  }
  int bcol = tid & 63, bks = tid >> 6;
  const float* W1e = W1 + (size_t)e * DM * HD;

  f32x4 acc[4][2] = {};
  float bv[3][8];

  auto issueB = [&](int tt, float* b) {
    const float* p = W1e + (size_t)(tt * 32 + bks * 8) * HD + h0 + bcol;
#pragma unroll
    for (int i = 0; i < 8; ++i) b[i] = p[(size_t)i * HD];
  };
  auto packwrite = [&](const float* b, int buf) {
    u16x8 o;
#pragma unroll
    for (int i = 0; i < 8; ++i) o[i] = f2b(b[i]);
    *(u16x8*)&Bsl[buf][bks][bcol][0] = o;
  };
  auto issueA = [&](int tt, int buf) {
#pragma unroll
    for (int q = 0; q < 2; ++q) {
      int idx = tid + q * 256;
      const unsigned short* ga = (tk[q] < 0)
          ? Xzero
          : Xb + (size_t)tk[q] * DM + tt * 32 + asg[q] * 8;
      gload_lds16(ga, (char*)&Asl[buf][0][0] + (size_t)idx * 16);
    }
  };
  auto compute = [&](int buf) {
    short8 a[4], b[2];
#pragma unroll
    for (int m = 0; m < 4; ++m) {
      int R = wr * 64 + m * 16 + l15;
      a[m] = *(const short8*)((const char*)&Asl[buf][0][0] + R * 64 + ((l4 ^ sw) << 4));
    }
#pragma unroll
    for (int n = 0; n < 2; ++n)
      b[n] = *(const short8*)&Bsl[buf][l4][wc * 32 + n * 16 + l15][0];
#pragma unroll
    for (int m = 0; m < 4; ++m)
#pragma unroll
      for (int n = 0; n < 2; ++n)
        acc[m][n] = __builtin_amdgcn_mfma_f32_16x16x32_bf16(a[m], b[n], acc[m][n], 0, 0, 0);
  };

  issueB(0, bv[0]);
  issueB(1, bv[1]);
  issueA(0, 0);
#pragma unroll
  for (int kt = 0; kt < 32; ++kt) {
    int buf = kt & 1;
    packwrite(bv[kt % 3], buf);
    __syncthreads();
    if (kt + 1 < 32) issueA(kt + 1, buf ^ 1);
    if (kt + 2 < 32) issueB(kt + 2, bv[(kt + 2) % 3]);
    compute(buf);
  }

  float bias[2];
#pragma unroll
  for (int n = 0; n < 2; ++n) bias[n] = b1[e * HD + h0 + wc * 32 + n * 16 + l15];
#pragma unroll
  for (int m = 0; m < 4; ++m) {
#pragma unroll
    for (int n = 0; n < 2; ++n) {
      int col = h0 + wc * 32 + n * 16 + l15;
#pragma unroll
      for (int j = 0; j < 4; ++j) {
        int row = row0 + wr * 64 + m * 16 + l4 * 4 + j;
        float x = acc[m][n][j] + bias[n];
        float g = 0.5f * x * (1.f + tanhf(0.7978845608f * (x + 0.044715f * x * x * x)));
        Hbuf[(size_t)row * HD + col] = f2b(g);
      }
    }
  }
}

// ---------------------------------------------------------------- ffn2
// R18 exact: both operands bf16 via pure global_load_lds; K-split x2;
// fp32 partials; bias ks==0 only.
__global__ __launch_bounds__(256, 6) void ffn2_mfma(
    const unsigned short* __restrict__ Hbuf,
    const unsigned short* __restrict__ W2C,
    const float* __restrict__ b2,
    const int* __restrict__ tile_expert, const int* __restrict__ tile_row0,
    const int* __restrict__ n_tiles,
    float* __restrict__ Ypart) {
  int lin  = blockIdx.x;
  int xcd  = lin & 7, slot = lin >> 3;
  int unit = xcd * 4 + slot / TMAX;        // 0..31
  int t    = slot % TMAX;
  if (t >= n_tiles[0]) return;
  int e    = tile_expert[t];
  int row0 = tile_row0[t];
  int d0   = (unit >> 1) * 64;
  int ks   = unit & 1;
  int kbase = ks * (HD / KSPL);            // 0 or 1024
  int kb0   = kbase >> 3;                  // chunk-row base
  __shared__ __align__(16) unsigned short Asl[2][128][32];
  __shared__ __align__(16) unsigned short Bsl[2][4][64][8];
  int tid = threadIdx.x, lane = tid & 63;
  int wid = tid >> 6, wr = wid >> 1, wc = wid & 1;
  int l15 = lane & 15, l4 = lane >> 4;
  int sw  = (l15 >> 1) & 3;

  int ar[2], asg[2];
#pragma unroll
  for (int q = 0; q < 2; ++q) {
    int idx = tid + q * 256;
    ar[q]  = idx >> 2;
    asg[q] = (idx & 3) ^ ((ar[q] >> 1) & 3);
  }
  int bcol = tid & 63, bks = tid >> 6;
  const unsigned short* W2e = W2C + (size_t)e * HD * DM;

  f32x4 acc[4][2] = {};

  auto issueAB = [&](int tt, int buf) {
#pragma unroll
    for (int q = 0; q < 2; ++q) {
      int idx = tid + q * 256;
      const unsigned short* ga =
          Hbuf + (size_t)(row0 + ar[q]) * HD + kbase + tt * 32 + asg[q] * 8;
      gload_lds16(ga, (char*)&Asl[buf][0][0] + (size_t)idx * 16);
    }
    const unsigned short* gb =
        W2e + ((size_t)(kb0 + tt * 4 + bks) * DM + d0 + bcol) * 8;
    gload_lds16(gb, (char*)&Bsl[buf][0][0] + (size_t)tid * 16);
  };
  auto compute = [&](int buf) {
    short8 a[4], b[2];
#pragma unroll
    for (int m = 0; m < 4; ++m) {
      int R = wr * 64 + m * 16 + l15;
      a[m] = *(const short8*)((const char*)&Asl[buf][0][0] + R * 64 + ((l4 ^ sw) << 4));
    }
#pragma unroll
    for (int n = 0; n < 2; ++n)
      b[n] = *(const short8*)&Bsl[buf][l4][wc * 32 + n * 16 + l15][0];
#pragma unroll
    for (int m = 0; m < 4; ++m)
#pragma unroll
      for (int n = 0; n < 2; ++n)
        acc[m][n] = __builtin_amdgcn_mfma_f32_16x16x32_bf16(a[m], b[n], acc[m][n], 0, 0, 0);
  };

  const int NT = HD / KSPL / 32;           // 32 K-steps
  issueAB(0, 0);
  for (int kt = 0; kt < NT; kt += 2) {
    __syncthreads();                       // drains vmcnt: buf0 ready
    if (kt + 1 < NT) issueAB(kt + 1, 1);
    compute(0);
    __syncthreads();                       // buf1 ready; buf0 free
    if (kt + 2 < NT) issueAB(kt + 2, 0);
    compute(1);
  }

  float bias[2];
#pragma unroll
  for (int n = 0; n < 2; ++n)
    bias[n] = (ks == 0) ? b2[e * DM + d0 + wc * 32 + n * 16 + l15] : 0.f;
  float* Yp = Ypart + (size_t)ks * RMAX * DM;
#pragma unroll
  for (int m = 0; m < 4; ++m) {
#pragma unroll
    for (int n = 0; n < 2; ++n) {
      int col = d0 + wc * 32 + n * 16 + l15;
#pragma unroll
      for (int j = 0; j < 4; ++j) {
        int row = row0 + wr * 64 + m * 16 + l4 * 4 + j;
        Yp[(size_t)row * DM + col] = acc[m][n][j] + bias[n];
      }
    }
  }
}

// ---------------------------------------------------------------- combine
__global__ void combine_kernel(const float* __restrict__ Ypart,
                               const int* __restrict__ inv_g,
                               const float* __restrict__ gate_w,
                               float* __restrict__ out) {
  int n = blockIdx.x;
  int r0 = inv_g[n * 2], r1 = inv_g[n * 2 + 1];
  float g0 = gate_w[n * 2], g1 = gate_w[n * 2 + 1];
  int i = threadIdx.x;
  const float4* y00 = (const float4*)(Ypart + (size_t)r0 * DM);
  const float4* y01 = (const float4*)(Ypart + (size_t)(RMAX + r0) * DM);
  const float4* y10 = (const float4*)(Ypart + (size_t)r1 * DM);
  const float4* y11 = (const float4*)(Ypart + (size_t)(RMAX + r1) * DM);
  float4 a0 = y00[i], a1 = y01[i], b0 = y10[i], b1 = y11[i];
  float4 rv;
  rv.x = g0 * (a0.x + a1.x) + g1 * (b0.x + b1.x);
  rv.y = g0 * (a0.y + a1.y) + g1 * (b0.y + b1.y);
  rv.z = g0 * (a0.z + a1.z) + g1 * (b0.z + b1.z);
  rv.w = g0 * (a0.w + a1.w) + g1 * (b0.w + b1.w);
  *(float4*)(out + (size_t)n * DM + i * 4) = rv;
}

// ---------------------------------------------------------------- launch
extern "C" void kernel_launch(void* const* d_in, const int* in_sizes, int n_in,
                              void* d_out, int out_size, void* d_ws, size_t ws_size,
                              hipStream_t stream) {
  const float* inp = (const float*)d_in[0];
  const float* Wg  = (const float*)d_in[1];
  const float* bg  = (const float*)d_in[2];
  const float* W1  = (const float*)d_in[3];
  const float* b1  = (const float*)d_in[4];
  const float* W2  = (const float*)d_in[5];
  const float* b2  = (const float*)d_in[6];
  float* out = (float*)d_out;

  char* ws = (char*)d_ws;
  size_t off = 0;
  auto alloc = [&](size_t bytes) {
    size_t o = off;
    off = (off + bytes + 255) & ~(size_t)255;
    return o;
  };
  int*   top_idx     = (int*)  (ws + alloc(N_TOK * 2 * sizeof(int)));
  float* gate_w      = (float*)(ws + alloc(N_TOK * 2 * sizeof(float)));
  int*   token_of    = (int*)  (ws + alloc(RMAX * sizeof(int)));
  int*   inv_g       = (int*)  (ws + alloc(N_TOK * 2 * sizeof(int)));
  int*   tile_expert = (int*)  (ws + alloc(TMAX * sizeof(int)));
  int*   tile_row0   = (int*)  (ws + alloc(TMAX * sizeof(int)));
  int*   n_tiles     = (int*)  (ws + alloc(sizeof(int)));
  unsigned short* Xzero = (unsigned short*)(ws + alloc(DM * 2));
  unsigned short* Xb    = (unsigned short*)(ws + alloc((size_t)N_TOK * DM * 2));
  unsigned short* W2C   = (unsigned short*)(ws + alloc((size_t)NE * HD * DM * 2));
  unsigned short* Hbuf  = (unsigned short*)(ws + alloc((size_t)RMAX * HD * 2));
  float*          Ypart = (float*)(ws + alloc((size_t)KSPL * RMAX * DM * 4));
  (void)ws_size;

  hipMemsetAsync(Xzero, 0, DM * 2, stream);
  prep_kernel<<<PREP_BLKS, 256, 0, stream>>>(inp, Wg, bg, top_idx, gate_w, Xb);
  group_kernel<<<1 + WCV2_BLKS, 1024, 0, stream>>>(
      top_idx, W2, token_of, inv_g, tile_expert, tile_row0, n_tiles, W2C);
  ffn1_mfma<<<8 * 4 * TMAX, 256, 0, stream>>>(
      Xb, W1, b1, Xzero, token_of, tile_expert, tile_row0, n_tiles, Hbuf);
  ffn2_mfma<<<8 * 4 * TMAX, 256, 0, stream>>>(
      Hbuf, W2C, b2, tile_expert, tile_row0, n_tiles, Ypart);
  combine_kernel<<<N_TOK, 256, 0, stream>>>(Ypart, inv_g, gate_w, out);
}